// Round 6
// baseline (405.797 us; speedup 1.0000x reference)
//
#include <hip/hip_runtime.h>
#include <math.h>

#define BB 4
#define HH 96
#define WW 96
#define CC 256
#define FF 256
#define HW (HH*WW)          // 9216
#define PTOT (BB*HW)        // 36864
#define NTAP 9

// workspace layout (float units):
//   w_frag: [16][72][64][8] bf16 (main conv B-frags)   294912
//   wof   : [2][72][64][8] bf16 (offset conv B-frags)   36864
//   xb16  : [PTOT][256] bf16                           4718592
#define WF_OFF  0
#define WOF_OFF (WF_OFF + 16*72*64*8/2)
#define XB_OFF  (WOF_OFF + 2*72*64*8/2)

typedef __attribute__((ext_vector_type(8))) short short8;   // 8 bf16
typedef __attribute__((ext_vector_type(4))) float floatx4;  // MFMA acc

struct alignas(16) F4 { float x, y, z, w; };
__device__ __forceinline__ F4 ldf4(const float* p) { return *(const F4*)p; }

__device__ __forceinline__ unsigned int pk2_bf16(float a, float b) {
    unsigned int ua = __float_as_uint(a); ua += 0x7FFFu + ((ua >> 16) & 1u);
    unsigned int ub = __float_as_uint(b); ub += 0x7FFFu + ((ub >> 16) & 1u);
    return (ua >> 16) | (ub & 0xFFFF0000u);
}
__device__ __forceinline__ float blo(unsigned int u) { return __uint_as_float(u << 16); }
__device__ __forceinline__ float bhi(unsigned int u) { return __uint_as_float(u & 0xFFFF0000u); }
__device__ __forceinline__ short8 zero8() { short8 v = {0,0,0,0,0,0,0,0}; return v; }

// Barrier WITHOUT vmcnt(0) drain: LDS producer/consumer only needs lgkmcnt(0);
// global loads stay in flight across it (backend inserts precise vmcnt at use).
__device__ __forceinline__ void lgkm_barrier() {
    __asm__ volatile("s_waitcnt lgkmcnt(0)\n\ts_barrier" ::: "memory");
}

// ---------------------------------------------------------------------------
// One prep kernel:
//   blocks [0,4608):    x fp32 -> bf16 (8 elems/thread)
//   blocks [4608,4896): w_conv -> bf16 B-fragments (MFMA load order)
//   blocks [4896,4932): w_off  -> bf16 B-fragments (o padded to 32)
__global__ __launch_bounds__(256) void k_prep(const float* __restrict__ x,
                                              const float* __restrict__ w_conv,
                                              const float* __restrict__ w_off,
                                              unsigned short* __restrict__ xb,
                                              unsigned short* __restrict__ w_frag,
                                              unsigned short* __restrict__ wof) {
    const int bid = blockIdx.x, t = threadIdx.x;
    if (bid < 4608) {
        const int id = bid * 256 + t;
        const F4 a = ldf4(x + (size_t)id * 8);
        const F4 b = ldf4(x + (size_t)id * 8 + 4);
        uint4 v;
        v.x = pk2_bf16(a.x, a.y); v.y = pk2_bf16(a.z, a.w);
        v.z = pk2_bf16(b.x, b.y); v.w = pk2_bf16(b.z, b.w);
        *(uint4*)(xb + (size_t)id * 8) = v;
    } else if (bid < 4896) {
        const int id = (bid - 4608) * 256 + t;      // 16*72*64
        const int lane = id & 63;
        const int kc   = (id >> 6) % 72;
        const int ft   = id / (72 * 64);
        const int f  = ft * 16 + (lane & 15);
        const int k0 = kc * 32 + (lane >> 4) * 8;
        unsigned int u[4];
#pragma unroll
        for (int jj = 0; jj < 4; ++jj) {
            float a = w_conv[(size_t)(k0 + 2 * jj) * FF + f];
            float b = w_conv[(size_t)(k0 + 2 * jj + 1) * FF + f];
            u[jj] = pk2_bf16(a, b);
        }
        uint4 v; v.x = u[0]; v.y = u[1]; v.z = u[2]; v.w = u[3];
        *(uint4*)(w_frag + (size_t)id * 8) = v;
    } else {
        const int id = (bid - 4896) * 256 + t;      // 2*72*64
        const int lane = id & 63;
        const int kc   = (id >> 6) % 72;
        const int nt   = id / (72 * 64);
        const int o  = nt * 16 + (lane & 15);
        const int k0 = kc * 32 + (lane >> 4) * 8;
        unsigned int u[4];
#pragma unroll
        for (int jj = 0; jj < 4; ++jj) {
            float a = (o < 27) ? w_off[(size_t)(k0 + 2 * jj) * 27 + o] : 0.f;
            float b = (o < 27) ? w_off[(size_t)(k0 + 2 * jj + 1) * 27 + o] : 0.f;
            u[jj] = pk2_bf16(a, b);
        }
        uint4 v; v.x = u[0]; v.y = u[1]; v.z = u[2]; v.w = u[3];
        *(uint4*)(wof + (size_t)id * 8) = v;
    }
}

// ---------------------------------------------------------------------------
// Fused DCN, 64 px x 256 f per block (B-frag traffic amortized 2x vs 32-px).
// Phase 1: offset/mask conv (MFMA) -> OM in LDS. Phase 2: bilinear gather ->
// bf16 LDS -> MFMA GEMM; lgkm-only barriers keep gathers in flight.
__global__ __launch_bounds__(256, 2) void k_fused(const unsigned short* __restrict__ xb,
                                                  const unsigned short* __restrict__ w_frag,
                                                  const unsigned short* __restrict__ wof,
                                                  const float* __restrict__ b_off,
                                                  const float* __restrict__ b_conv,
                                                  float* __restrict__ out) {
    __shared__ unsigned short S[64 * 264];      // 33.8 KB, px stride 264 (pad 8)
    __shared__ float OM[64][28];                // offset-conv raw outputs (o<27)

    const int t    = threadIdx.x;
    const int lane = t & 63;
    const int wv   = t >> 6;
    const int tb   = (blockIdx.x & 7) * 72 + (blockIdx.x >> 3);   // XCD-local
    const int pb   = tb * 64;
    const size_t ibase = (size_t)(pb / HW) * HW * CC;
    const int ml = lane & 15, q = lane >> 4;

    // ---------------- phase 1: offset conv GEMM (wave wv -> m-tile wv) ----------------
    {
        const int px = pb + wv * 16 + ml;
        const int rr = px % HW;
        const int py = rr / WW;
        const int pxx = rr - py * WW;
        floatx4 acc0 = {0.f, 0.f, 0.f, 0.f}, acc1 = {0.f, 0.f, 0.f, 0.f};
        const short8* W = (const short8*)wof;
        for (int tap = 0; tap < NTAP; ++tap) {
            const int sy = py + tap / 3 - 1;
            const int sx = pxx + tap % 3 - 1;
            const bool valid = (sy >= 0) && (sy < HH) && (sx >= 0) && (sx < WW);
            const unsigned short* rowp = xb + ibase + (size_t)(sy * WW + sx) * CC + q * 8;
#pragma unroll
            for (int c8 = 0; c8 < 8; ++c8) {
                short8 a = valid ? *(const short8*)(rowp + c8 * 32) : zero8();
                acc0 = __builtin_amdgcn_mfma_f32_16x16x32_bf16(
                    a, W[(size_t)(0 * 72 + tap * 8 + c8) * 64 + lane], acc0, 0, 0, 0);
                acc1 = __builtin_amdgcn_mfma_f32_16x16x32_bf16(
                    a, W[(size_t)(1 * 72 + tap * 8 + c8) * 64 + lane], acc1, 0, 0, 0);
            }
        }
#pragma unroll
        for (int nt = 0; nt < 2; ++nt) {
            const int o = nt * 16 + ml;         // C-layout: px = wv*16+q*4+r
            if (o < 27) {
                const float bo = b_off[o];
                const floatx4 a = nt ? acc1 : acc0;
#pragma unroll
                for (int r = 0; r < 4; ++r)
                    OM[wv * 16 + q * 4 + r][o] = a[r] + bo;
            }
        }
    }
    __syncthreads();

    // ---------------- phase 2 ----------------
    const int px_s = t >> 2;                    // staging pixel (0..63)
    const int c4   = t & 3;                     // 64-ch slice
    const int rr2  = (pb + px_s) % HW;
    const int spy  = rr2 / WW;
    const int spxx = rr2 - spy * WW;

    floatx4 acc[4][4];                          // [nt][mt]
#pragma unroll
    for (int i = 0; i < 4; ++i)
#pragma unroll
        for (int j = 0; j < 4; ++j) acc[i][j] = floatx4{0.f, 0.f, 0.f, 0.f};

    const short8* Wl = (const short8*)w_frag + lane;

    uint4 GA[8], GB[8], GC[8], GD[8];           // 64 ch x 4 corners in flight
    float F00, F01, F10, F11;

    auto meta_issue = [&](int tap) {
        const float dy  = OM[px_s][tap];
        const float dxv = OM[px_s][tap + 9];
        const float mr  = OM[px_s][tap + 18];
        const float m = 1.f / (1.f + __expf(-mr));
        const float yy = (float)(spy + tap / 3 - 1) + dy;
        const float xx = (float)(spxx + tap % 3 - 1) + dxv;
        const float y0f = floorf(yy), x0f = floorf(xx);
        const int y0 = (int)y0f, x0 = (int)x0f;
        const float wy1 = yy - y0f, wx1 = xx - x0f;
        const float wy0 = 1.f - wy1, wx0 = 1.f - wx1;
        const bool vy0 = (y0 >= 0) && (y0 < HH);
        const bool vy1 = (y0 + 1 >= 0) && (y0 + 1 < HH);
        const bool vx0 = (x0 >= 0) && (x0 < WW);
        const bool vx1 = (x0 + 1 >= 0) && (x0 + 1 < WW);
        const int y0c = min(max(y0, 0), HH - 1);
        const int y1c = min(max(y0 + 1, 0), HH - 1);
        const int x0c = min(max(x0, 0), WW - 1);
        const int x1c = min(max(x0 + 1, 0), WW - 1);
        F00 = (vy0 && vx0) ? wy0 * wx0 * m : 0.f;
        F01 = (vy0 && vx1) ? wy0 * wx1 * m : 0.f;
        F10 = (vy1 && vx0) ? wy1 * wx0 * m : 0.f;
        F11 = (vy1 && vx1) ? wy1 * wx1 * m : 0.f;
        const unsigned short* p00 = xb + ibase + (size_t)(y0c * WW + x0c) * CC + c4 * 64;
        const unsigned short* p01 = xb + ibase + (size_t)(y0c * WW + x1c) * CC + c4 * 64;
        const unsigned short* p10 = xb + ibase + (size_t)(y1c * WW + x0c) * CC + c4 * 64;
        const unsigned short* p11 = xb + ibase + (size_t)(y1c * WW + x1c) * CC + c4 * 64;
#pragma unroll
        for (int j = 0; j < 8; ++j) {
            GA[j] = *(const uint4*)(p00 + j * 8);
            GB[j] = *(const uint4*)(p01 + j * 8);
            GC[j] = *(const uint4*)(p10 + j * 8);
            GD[j] = *(const uint4*)(p11 + j * 8);
        }
    };

    auto blend_store = [&]() {
        unsigned short* Srow = &S[px_s * 264 + c4 * 64];
#pragma unroll
        for (int j = 0; j < 8; ++j) {
            uint4 R;
            R.x = pk2_bf16(blo(GA[j].x)*F00 + blo(GB[j].x)*F01 + blo(GC[j].x)*F10 + blo(GD[j].x)*F11,
                           bhi(GA[j].x)*F00 + bhi(GB[j].x)*F01 + bhi(GC[j].x)*F10 + bhi(GD[j].x)*F11);
            R.y = pk2_bf16(blo(GA[j].y)*F00 + blo(GB[j].y)*F01 + blo(GC[j].y)*F10 + blo(GD[j].y)*F11,
                           bhi(GA[j].y)*F00 + bhi(GB[j].y)*F01 + bhi(GC[j].y)*F10 + bhi(GD[j].y)*F11);
            R.z = pk2_bf16(blo(GA[j].z)*F00 + blo(GB[j].z)*F01 + blo(GC[j].z)*F10 + blo(GD[j].z)*F11,
                           bhi(GA[j].z)*F00 + bhi(GB[j].z)*F01 + bhi(GC[j].z)*F10 + bhi(GD[j].z)*F11);
            R.w = pk2_bf16(blo(GA[j].w)*F00 + blo(GB[j].w)*F01 + blo(GC[j].w)*F10 + blo(GD[j].w)*F11,
                           bhi(GA[j].w)*F00 + bhi(GB[j].w)*F01 + bhi(GC[j].w)*F10 + bhi(GD[j].w)*F11);
            *(uint4*)(Srow + j * 8) = R;
        }
    };

    meta_issue(0);    // tap-0 gathers in flight

    for (int tap = 0; tap < NTAP; ++tap) {
        blend_store();                      // waits only this tap's gathers
        lgkm_barrier();                     // S visible; later loads stay in flight
        if (tap + 1 < NTAP) meta_issue(tap + 1);   // next gathers fly over MFMAs

        const size_t wb = ((size_t)(wv * 4) * 72 + tap * 8) * 64;
#pragma unroll
        for (int kc = 0; kc < 8; ++kc) {
            short8 a[4];
#pragma unroll
            for (int mt = 0; mt < 4; ++mt)
                a[mt] = *(const short8*)&S[(mt * 16 + ml) * 264 + kc * 32 + q * 8];
#pragma unroll
            for (int nt = 0; nt < 4; ++nt) {
                short8 b = Wl[wb + (size_t)(nt * 72 + kc) * 64];
#pragma unroll
                for (int mt = 0; mt < 4; ++mt)
                    acc[nt][mt] = __builtin_amdgcn_mfma_f32_16x16x32_bf16(a[mt], b, acc[nt][mt], 0, 0, 0);
            }
        }
        if (tap + 1 < NTAP) lgkm_barrier(); // all waves done reading S before overwrite
    }

    // epilogue: col = lane&15 (f), row = (lane>>4)*4+reg (px)
#pragma unroll
    for (int nt = 0; nt < 4; ++nt) {
        const int f = wv * 64 + nt * 16 + ml;
        const float bc = b_conv[f];
#pragma unroll
        for (int mt = 0; mt < 4; ++mt) {
#pragma unroll
            for (int r = 0; r < 4; ++r) {
                const int px = pb + mt * 16 + q * 4 + r;
                out[(size_t)px * FF + f] = acc[nt][mt][r] + bc;
            }
        }
    }
}

// ---------------------------------------------------------------------------
extern "C" void kernel_launch(void* const* d_in, const int* in_sizes, int n_in,
                              void* d_out, int out_size, void* d_ws, size_t ws_size,
                              hipStream_t stream) {
    const float* x      = (const float*)d_in[0];
    const float* w_off  = (const float*)d_in[1];
    const float* b_off  = (const float*)d_in[2];
    const float* w_conv = (const float*)d_in[3];
    const float* b_conv = (const float*)d_in[4];
    float* out = (float*)d_out;
    float* ws  = (float*)d_ws;

    unsigned short* w_frag = (unsigned short*)(ws + WF_OFF);
    unsigned short* wof    = (unsigned short*)(ws + WOF_OFF);
    unsigned short* xb     = (unsigned short*)(ws + XB_OFF);

    hipLaunchKernelGGL(k_prep, dim3(4932), dim3(256), 0, stream,
                       x, w_conv, w_off, xb, w_frag, wof);
    hipLaunchKernelGGL(k_fused, dim3(PTOT / 64), dim3(256), 0, stream,
                       xb, w_frag, wof, b_off, b_conv, out);
}

// Round 8
// 237.304 us; speedup vs baseline: 1.7100x; 1.7100x over previous
//
#include <hip/hip_runtime.h>
#include <math.h>

#define BB 4
#define HH 96
#define WW 96
#define CC 256
#define FF 256
#define HW (HH*WW)          // 9216
#define PTOT (BB*HW)        // 36864
#define NTAP 9

// workspace layout (float units):
//   w_frag: [16][72][64][8] bf16 (main conv B-frags)   294912
//   wof   : [2][72][64][8] bf16 (offset conv B-frags)   36864
//   xb16  : [PTOT][256] bf16                           4718592
#define WF_OFF  0
#define WOF_OFF (WF_OFF + 16*72*64*8/2)
#define XB_OFF  (WOF_OFF + 2*72*64*8/2)

typedef __attribute__((ext_vector_type(8))) short short8;   // 8 bf16
typedef __attribute__((ext_vector_type(4))) float floatx4;  // MFMA acc

struct alignas(16) F4 { float x, y, z, w; };
__device__ __forceinline__ F4 ldf4(const float* p) { return *(const F4*)p; }

__device__ __forceinline__ unsigned int pk2_bf16(float a, float b) {
    unsigned int ua = __float_as_uint(a); ua += 0x7FFFu + ((ua >> 16) & 1u);
    unsigned int ub = __float_as_uint(b); ub += 0x7FFFu + ((ub >> 16) & 1u);
    return (ua >> 16) | (ub & 0xFFFF0000u);
}
__device__ __forceinline__ float blo(unsigned int u) { return __uint_as_float(u << 16); }
__device__ __forceinline__ float bhi(unsigned int u) { return __uint_as_float(u & 0xFFFF0000u); }
__device__ __forceinline__ short8 zero8() { short8 v = {0,0,0,0,0,0,0,0}; return v; }

// Barrier WITHOUT vmcnt(0) drain: LDS producer/consumer only needs lgkmcnt(0);
// global loads stay in flight across it (backend inserts precise vmcnt at use).
__device__ __forceinline__ void lgkm_barrier() {
    __asm__ volatile("s_waitcnt lgkmcnt(0)\n\ts_barrier" ::: "memory");
}

// ---------------------------------------------------------------------------
// One prep kernel:
//   blocks [0,4608):    x fp32 -> bf16 (8 elems/thread)
//   blocks [4608,4896): w_conv -> bf16 B-fragments (MFMA load order)
//   blocks [4896,4932): w_off  -> bf16 B-fragments (o padded to 32)
__global__ __launch_bounds__(256) void k_prep(const float* __restrict__ x,
                                              const float* __restrict__ w_conv,
                                              const float* __restrict__ w_off,
                                              unsigned short* __restrict__ xb,
                                              unsigned short* __restrict__ w_frag,
                                              unsigned short* __restrict__ wof) {
    const int bid = blockIdx.x, t = threadIdx.x;
    if (bid < 4608) {
        const int id = bid * 256 + t;
        const F4 a = ldf4(x + (size_t)id * 8);
        const F4 b = ldf4(x + (size_t)id * 8 + 4);
        uint4 v;
        v.x = pk2_bf16(a.x, a.y); v.y = pk2_bf16(a.z, a.w);
        v.z = pk2_bf16(b.x, b.y); v.w = pk2_bf16(b.z, b.w);
        *(uint4*)(xb + (size_t)id * 8) = v;
    } else if (bid < 4896) {
        const int id = (bid - 4608) * 256 + t;      // 16*72*64
        const int lane = id & 63;
        const int kc   = (id >> 6) % 72;
        const int ft   = id / (72 * 64);
        const int f  = ft * 16 + (lane & 15);
        const int k0 = kc * 32 + (lane >> 4) * 8;
        unsigned int u[4];
#pragma unroll
        for (int jj = 0; jj < 4; ++jj) {
            float a = w_conv[(size_t)(k0 + 2 * jj) * FF + f];
            float b = w_conv[(size_t)(k0 + 2 * jj + 1) * FF + f];
            u[jj] = pk2_bf16(a, b);
        }
        uint4 v; v.x = u[0]; v.y = u[1]; v.z = u[2]; v.w = u[3];
        *(uint4*)(w_frag + (size_t)id * 8) = v;
    } else {
        const int id = (bid - 4896) * 256 + t;      // 2*72*64
        const int lane = id & 63;
        const int kc   = (id >> 6) % 72;
        const int nt   = id / (72 * 64);
        const int o  = nt * 16 + (lane & 15);
        const int k0 = kc * 32 + (lane >> 4) * 8;
        unsigned int u[4];
#pragma unroll
        for (int jj = 0; jj < 4; ++jj) {
            float a = (o < 27) ? w_off[(size_t)(k0 + 2 * jj) * 27 + o] : 0.f;
            float b = (o < 27) ? w_off[(size_t)(k0 + 2 * jj + 1) * 27 + o] : 0.f;
            u[jj] = pk2_bf16(a, b);
        }
        uint4 v; v.x = u[0]; v.y = u[1]; v.z = u[2]; v.w = u[3];
        *(uint4*)(wof + (size_t)id * 8) = v;
    }
}

// ---------------------------------------------------------------------------
// Fused DCN, 32 px x 256 f per block. Control flow is r5's (known-good):
//   meta_issue(0); loop { blend_store; barrier; meta_issue(tap+1); MFMA; barrier; }
// ONLY the staging map changed vs r5: wave = 2 px x 32 ch-slices, so each
// gather instruction's 64 lanes cover exactly 2 contiguous 512B rows
// (TA-friendly) instead of 8 scattered 128B segments.
__global__ __launch_bounds__(256) void k_fused(const unsigned short* __restrict__ xb,
                                               const unsigned short* __restrict__ w_frag,
                                               const unsigned short* __restrict__ wof,
                                               const float* __restrict__ b_off,
                                               const float* __restrict__ b_conv,
                                               float* __restrict__ out) {
    __shared__ unsigned short S[32 * 264];      // 16.9 KB, px stride 264 (pad 8)
    __shared__ float OM[32][28];                // offset-conv raw outputs (o<27)

    const int t    = threadIdx.x;
    const int lane = t & 63;
    const int wv   = t >> 6;
    const int tb   = (blockIdx.x & 7) * 144 + (blockIdx.x >> 3);   // XCD-local
    const int pb   = tb * 32;
    const size_t ibase = (size_t)(pb / HW) * HW * CC;
    const int ml = lane & 15, q = lane >> 4;
    // all 32 px of the block live in ONE image row (96 % 32 == 0):
    const int rr0  = pb % HW;
    const int spy  = rr0 / WW;          // row
    const int xb0  = rr0 - spy * WW;    // first column

    // ---------------- phase 1: offset conv GEMM (o padded to 32) ----------------
    {
        const int mt = wv & 1, nt = wv >> 1;    // wave -> (m-tile, n-tile)
        const int px = pb + mt * 16 + ml;
        const int rr = px % HW;
        const int py = rr / WW;
        const int pxx = rr - py * WW;
        floatx4 acc1 = {0.f, 0.f, 0.f, 0.f};
        const short8* W = (const short8*)wof;
        for (int tap = 0; tap < NTAP; ++tap) {
            const int sy = py + tap / 3 - 1;
            const int sx = pxx + tap % 3 - 1;
            const bool valid = (sy >= 0) && (sy < HH) && (sx >= 0) && (sx < WW);
            const unsigned short* rowp = xb + ibase + (size_t)(sy * WW + sx) * CC + q * 8;
#pragma unroll
            for (int c8 = 0; c8 < 8; ++c8) {
                short8 a = valid ? *(const short8*)(rowp + c8 * 32) : zero8();
                acc1 = __builtin_amdgcn_mfma_f32_16x16x32_bf16(
                    a, W[(size_t)(nt * 72 + tap * 8 + c8) * 64 + lane], acc1, 0, 0, 0);
            }
        }
        const int o = nt * 16 + ml;             // C-layout: px = mt*16+q*4+r
        if (o < 27) {
            const float bo = b_off[o];
#pragma unroll
            for (int r = 0; r < 4; ++r)
                OM[mt * 16 + q * 4 + r][o] = acc1[r] + bo;
        }
    }
    __syncthreads();

    // ---------------- phase 2 ----------------
    const int c16  = lane & 31;                 // 16B channel slice (0..31)
    const int psub = lane >> 5;                 // which of this wave's 2 px

    floatx4 acc[4][2];
#pragma unroll
    for (int i = 0; i < 4; ++i) { acc[i][0] = floatx4{0.f,0.f,0.f,0.f}; acc[i][1] = floatx4{0.f,0.f,0.f,0.f}; }

    const short8* Wl = (const short8*)w_frag + lane;

    // per-tap staging state: 4 rounds, all indices compile-time constant
    uint4 GA[4], GB[4], GC[4], GD[4];
    float fwv[4][4];

    // issue ALL 4 rounds' meta + corner loads for tap tp.
    // Round r covers pixel p = r*8 + wv*2 + psub, channel slice c16.
    auto meta_issue = [&](int tp) {
#pragma unroll
        for (int r = 0; r < 4; ++r) {
            const int p  = r * 8 + wv * 2 + psub;
            const float dy  = OM[p][tp];
            const float dxv = OM[p][tp + 9];
            const float mr  = OM[p][tp + 18];
            const float m = 1.f / (1.f + __expf(-mr));
            const float yy = (float)(spy + tp / 3 - 1) + dy;
            const float xx = (float)(xb0 + p + tp % 3 - 1) + dxv;
            const float y0f = floorf(yy), x0f = floorf(xx);
            const int y0 = (int)y0f, x0 = (int)x0f;
            const float wy1 = yy - y0f, wx1 = xx - x0f;
            const float wy0 = 1.f - wy1, wx0 = 1.f - wx1;
            const bool vy0 = (y0 >= 0) && (y0 < HH);
            const bool vy1 = (y0 + 1 >= 0) && (y0 + 1 < HH);
            const bool vx0 = (x0 >= 0) && (x0 < WW);
            const bool vx1 = (x0 + 1 >= 0) && (x0 + 1 < WW);
            const int y0c = min(max(y0, 0), HH - 1);
            const int y1c = min(max(y0 + 1, 0), HH - 1);
            const int x0c = min(max(x0, 0), WW - 1);
            const int x1c = min(max(x0 + 1, 0), WW - 1);
            fwv[r][0] = (vy0 && vx0) ? wy0 * wx0 * m : 0.f;
            fwv[r][1] = (vy0 && vx1) ? wy0 * wx1 * m : 0.f;
            fwv[r][2] = (vy1 && vx0) ? wy1 * wx0 * m : 0.f;
            fwv[r][3] = (vy1 && vx1) ? wy1 * wx1 * m : 0.f;
            const unsigned short* base = xb + ibase;
            GA[r] = *(const uint4*)(base + (size_t)(y0c * WW + x0c) * CC + c16 * 8);
            GB[r] = *(const uint4*)(base + (size_t)(y0c * WW + x1c) * CC + c16 * 8);
            GC[r] = *(const uint4*)(base + (size_t)(y1c * WW + x0c) * CC + c16 * 8);
            GD[r] = *(const uint4*)(base + (size_t)(y1c * WW + x1c) * CC + c16 * 8);
        }
    };

    auto blend_store = [&]() {
#pragma unroll
        for (int r = 0; r < 4; ++r) {
            const int p = r * 8 + wv * 2 + psub;
            const float F00 = fwv[r][0], F01 = fwv[r][1], F10 = fwv[r][2], F11 = fwv[r][3];
            const uint4 A = GA[r], B = GB[r], C = GC[r], D = GD[r];
            uint4 R;
            R.x = pk2_bf16(blo(A.x)*F00 + blo(B.x)*F01 + blo(C.x)*F10 + blo(D.x)*F11,
                           bhi(A.x)*F00 + bhi(B.x)*F01 + bhi(C.x)*F10 + bhi(D.x)*F11);
            R.y = pk2_bf16(blo(A.y)*F00 + blo(B.y)*F01 + blo(C.y)*F10 + blo(D.y)*F11,
                           bhi(A.y)*F00 + bhi(B.y)*F01 + bhi(C.y)*F10 + bhi(D.y)*F11);
            R.z = pk2_bf16(blo(A.z)*F00 + blo(B.z)*F01 + blo(C.z)*F10 + blo(D.z)*F11,
                           bhi(A.z)*F00 + bhi(B.z)*F01 + bhi(C.z)*F10 + bhi(D.z)*F11);
            R.w = pk2_bf16(blo(A.w)*F00 + blo(B.w)*F01 + blo(C.w)*F10 + blo(D.w)*F11,
                           bhi(A.w)*F00 + bhi(B.w)*F01 + bhi(C.w)*F10 + bhi(D.w)*F11);
            *(uint4*)&S[p * 264 + c16 * 8] = R;
        }
    };

    meta_issue(0);    // tap-0 gathers in flight

    for (int tap = 0; tap < NTAP; ++tap) {
        blend_store();                      // waits only this tap's gathers
        lgkm_barrier();                     // S visible; globals stay in flight
        if (tap + 1 < NTAP) meta_issue(tap + 1);   // next gathers fly over MFMAs

        // ---- MFMA over this tap's 256 channels
        const size_t wb = ((size_t)(wv * 4) * 72 + tap * 8) * 64;
#pragma unroll
        for (int kc = 0; kc < 8; ++kc) {
            short8 a0 = *(const short8*)&S[ml * 264 + kc * 32 + q * 8];
            short8 a1 = *(const short8*)&S[(16 + ml) * 264 + kc * 32 + q * 8];
#pragma unroll
            for (int nt = 0; nt < 4; ++nt) {
                short8 b = Wl[wb + (size_t)(nt * 72 + kc) * 64];
                acc[nt][0] = __builtin_amdgcn_mfma_f32_16x16x32_bf16(a0, b, acc[nt][0], 0, 0, 0);
                acc[nt][1] = __builtin_amdgcn_mfma_f32_16x16x32_bf16(a1, b, acc[nt][1], 0, 0, 0);
            }
        }
        if (tap + 1 < NTAP) lgkm_barrier(); // S consumed before overwrite
    }

    // epilogue: col = lane&15 (f), row = (lane>>4)*4+reg (px)
#pragma unroll
    for (int nt = 0; nt < 4; ++nt) {
        const int f = wv * 64 + nt * 16 + ml;
        const float bc = b_conv[f];
#pragma unroll
        for (int mt = 0; mt < 2; ++mt) {
#pragma unroll
            for (int r = 0; r < 4; ++r) {
                const int px = pb + mt * 16 + q * 4 + r;
                out[(size_t)px * FF + f] = acc[nt][mt][r] + bc;
            }
        }
    }
}

// ---------------------------------------------------------------------------
extern "C" void kernel_launch(void* const* d_in, const int* in_sizes, int n_in,
                              void* d_out, int out_size, void* d_ws, size_t ws_size,
                              hipStream_t stream) {
    const float* x      = (const float*)d_in[0];
    const float* w_off  = (const float*)d_in[1];
    const float* b_off  = (const float*)d_in[2];
    const float* w_conv = (const float*)d_in[3];
    const float* b_conv = (const float*)d_in[4];
    float* out = (float*)d_out;
    float* ws  = (float*)d_ws;

    unsigned short* w_frag = (unsigned short*)(ws + WF_OFF);
    unsigned short* wof    = (unsigned short*)(ws + WOF_OFF);
    unsigned short* xb     = (unsigned short*)(ws + XB_OFF);

    hipLaunchKernelGGL(k_prep, dim3(4932), dim3(256), 0, stream,
                       x, w_conv, w_off, xb, w_frag, wof);
    hipLaunchKernelGGL(k_fused, dim3(PTOT / 32), dim3(256), 0, stream,
                       xb, w_frag, wof, b_off, b_conv, out);
}